// Round 12
// baseline (174.489 us; speedup 1.0000x reference)
//
#include <hip/hip_runtime.h>
#include <hip/hip_bf16.h>
#include <math.h>

#define N     12
#define HID   64
#define STP   68     // fp32 row stride for enc h1/h2 (272 B rows)
#define XST   72     // bf16 row stride (144 B rows; 36-dword shift -> benign conflicts)
#define SLOPE 0.2f
#define ALPHA 0.1f

typedef float v2f __attribute__((ext_vector_type(2)));
typedef float v4f __attribute__((ext_vector_type(4)));
typedef int   i4  __attribute__((ext_vector_type(4)));
typedef short v8s __attribute__((ext_vector_type(8)));

static __device__ __forceinline__ v8s as_v8s(i4 v) {
    union { i4 a; v8s b; } u; u.a = v; return u.b;
}
static __device__ __forceinline__ unsigned short f2bf(float f) {
    __hip_bfloat16 h = __float2bfloat16(f);
    return *(unsigned short*)&h;
}
static __device__ __forceinline__ float bf2f(unsigned short u) {
    return __uint_as_float((unsigned)u << 16);
}

// flat output offsets (float32 elements)
#define OUT0 0
#define OUT1 196608
#define OUT2 245760
#define OUT3 442368
#define OUT4 491520

// ws layout (float offsets):
//   [0,4096)       enc_w2 transposed fp32 (enc stays fp32: latent feeds Gabriel
//                  d2>r2 comparisons -> adjacency must be deterministic)
//   [4096,16384)   6 GAT matrices pre-packed in MFMA B-frag layout, bf16
//   [16384,16640)  labT fp32: labT[c*64+h] = lab_w[h*4+c]
__global__ void prep_kernel(const float* __restrict__ enc_w2,
                            const float* __restrict__ g2_wl, const float* __restrict__ g2_wr,
                            const float* __restrict__ g3_wl, const float* __restrict__ g3_wr,
                            const float* __restrict__ g4_wl, const float* __restrict__ g4_wr,
                            const float* __restrict__ lab_w,
                            float* __restrict__ ws) {
    int t = threadIdx.x;
    int bx = blockIdx.x;
    if (bx < 64) { ws[t*64 + bx] = enc_w2[bx*64 + t]; return; }
    if (bx == 112) {
        #pragma unroll
        for (int c = 0; c < 4; c++) ws[16384 + c*64 + t] = lab_w[t*4 + c];
        return;
    }
    int idx = bx - 64;
    int mat = idx >> 3, rem = idx & 7;
    int kt = rem >> 2, nt = rem & 3;
    const float* src;
    switch (mat) {
        case 0: src = g2_wl; break;
        case 1: src = g2_wr; break;
        case 2: src = g3_wl; break;
        case 3: src = g3_wr; break;
        case 4: src = g4_wl; break;
        default: src = g4_wr; break;
    }
    int quad = t >> 4, col = t & 15;
    int n = nt*16 + col;
    unsigned* dst = (unsigned*)(ws + 4096) + mat*2048 + (kt*4+nt)*256 + t*4;
    #pragma unroll
    for (int jp = 0; jp < 4; jp++) {
        int k0 = kt*32 + quad*8 + 2*jp;
        dst[jp] = (unsigned)f2bf(src[(k0+0)*64 + n]) | ((unsigned)f2bf(src[(k0+1)*64 + n]) << 16);
    }
}

// One graph per 64-lane wave (R7: multi-wave blocks convoy).
// R12 MODEL: kernel is DS-pipe-throughput bound (per-CU LDS pipe shared by 16
// waves; ~6-7k DS cycles/wave x 16 ~= the 117k-cycle wall; explains R9's win
// and R10/R11's neutrality). So: minimize DS instructions.
//  - xl/xr/x as bf16 (score div reads halved; stage/head traffic halved)
//  - gab k-loop coordinates hoisted to registers (const-indexed -> stays VGPR)
//  - enc1 reads batch from global (uniform -> scalar/VMEM pipe, zero DS)
//  - enc fp32 buffers overlap GAT bf16 buffers (disjoint lifetimes): 7424 B LDS
// R3/R4: keep 16-iter fp32 K-loops ROLLED. R8: sparse score. R9: MFMA stages.
// R10: softmax fused away (exp/rowsum; diag always present, e=O(1)).
template<bool TW>
__global__ __launch_bounds__(64, 3) void gae_kernel(
    const float* __restrict__ batch,
    const float* __restrict__ enc_w1, const float* __restrict__ enc_b1,
    const float* __restrict__ enc_w2, const float* __restrict__ enc_b2,
    const float* __restrict__ enc_w3, const float* __restrict__ enc_b3,
    const float* __restrict__ g1_wl, const float* __restrict__ g1_wr,
    const float* __restrict__ g1_att, const float* __restrict__ g1_b,
    const float* __restrict__ g2_wl, const float* __restrict__ g2_wr,
    const float* __restrict__ g2_att, const float* __restrict__ g2_b,
    const float* __restrict__ g3_wl, const float* __restrict__ g3_wr,
    const float* __restrict__ g3_att, const float* __restrict__ g3_b,
    const float* __restrict__ g4_wl, const float* __restrict__ g4_wr,
    const float* __restrict__ g4_att, const float* __restrict__ g4_b,
    const float* __restrict__ lab_w, const float* __restrict__ lab_b,
    const float* __restrict__ val_w, const float* __restrict__ val_b,
    const float* __restrict__ skip_w, const float* __restrict__ skip_b,
    const float* __restrict__ wsT,
    float* __restrict__ out)
{
    const int b = blockIdx.x;
    const int t = threadIdx.x;

    // enc phase: h1 [0,3264), h2 [3264,6528) fp32
    // GAT phase: xl16 [0,1728), xr16 [1728,3456), xB16 [3456,5184) bf16
    __shared__ __align__(16) unsigned char smem[7424];
    float* h1 = (float*)smem;
    float* h2 = (float*)(smem + 3264);
    unsigned short* xl16 = (unsigned short*)smem;
    unsigned short* xr16 = (unsigned short*)(smem + 1728);
    unsigned short* xB16 = (unsigned short*)(smem + 3456);
    float* pool  = (float*)(smem + 6528);   // lat(36) -> exp(e)(144)
    float* att_s = (float*)(smem + 7104);
    unsigned char* pairs8 = smem + 7360;

    const v2f z2 = {0.f, 0.f};
    const v4f z4 = {0.f, 0.f, 0.f, 0.f};
    const v2f sl2 = {SLOPE, SLOPE};

    // score-pair decomposition (144 pairs, 3 slots of 64/64/16)
    const int p0 = t,        i0 = p0 / N, j0 = p0 - i0*N;
    const int p1 = t + 64,   i1 = p1 / N, j1 = p1 - i1*N;
    const int p2 = (t < 16) ? (t + 128) : 143;
    const int i2 = p2 / N,   j2 = p2 - i2*N;

    // ---- passthrough outputs 0/1 (divergent global reads; no LDS staging) ----
    if (t < N*5) {
        float v = batch[b*(N*5) + t];
        int i = t / 5, f = t - i*5;
        if (f < 4) out[OUT0 + (size_t)b*(N*4) + i*4 + f] = v;
        else       out[OUT1 + (size_t)b*N + i] = v;
    }

    // ---- encoder layer 1 (batch read from global: uniform -> scalar pipe) ----
    {
        float acc[N];
        float bias = enc_b1[t];
        #pragma unroll
        for (int i=0;i<N;i++) acc[i] = bias;
        const float* brow = batch + b*(N*5);
        #pragma unroll
        for (int f=0; f<5; f++) {
            float w = enc_w1[f*HID + t];
            #pragma unroll
            for (int i=0;i<N;i++) acc[i] = fmaf(brow[i*5+f], w, acc[i]);
        }
        #pragma unroll
        for (int i=0;i<N;i++) h1[i*STP + t] = fmaxf(acc[i], 0.f);
    }
    __syncthreads();

    // ---- encoder layer 2 (fp32; K-loop ROLLED) ----
    {
        v2f acc[N];
        #pragma unroll
        for (int i=0;i<N;i++) acc[i] = z2;
        const float* w2p = TW ? (wsT + t*HID) : nullptr;
        for (int c=0;c<HID;c+=4) {
            v2f w01, w23;
            if (TW) {
                v4f w4 = *reinterpret_cast<const v4f*>(&w2p[c]);
                w01 = w4.xy; w23 = w4.zw;
            } else {
                w01 = (v2f){enc_w2[(c+0)*HID+t], enc_w2[(c+1)*HID+t]};
                w23 = (v2f){enc_w2[(c+2)*HID+t], enc_w2[(c+3)*HID+t]};
            }
            #pragma unroll
            for (int i=0;i<N;i++) {
                v4f xv = *reinterpret_cast<const v4f*>(&h1[i*STP + c]);
                acc[i] = __builtin_elementwise_fma(xv.xy, w01, acc[i]);
                acc[i] = __builtin_elementwise_fma(xv.zw, w23, acc[i]);
            }
        }
        float bias = enc_b2[t];
        #pragma unroll
        for (int i=0;i<N;i++) h2[i*STP + t] = fmaxf(bias + acc[i].x + acc[i].y, 0.f);
    }
    __syncthreads();

    // ---- latent = h2 @ W3 + b3 (lanes 0..35) -> pool[0..35] ----
    if (t < N*3) {
        int i = t / 3, c = t - i*3;
        float acc = enc_b3[c];
        for (int k=0;k<HID;k+=4) {
            v4f xv = *reinterpret_cast<const v4f*>(&h2[i*STP + k]);
            acc = fmaf(xv.x, enc_w3[(k+0)*3+c], acc);
            acc = fmaf(xv.y, enc_w3[(k+1)*3+c], acc);
            acc = fmaf(xv.z, enc_w3[(k+2)*3+c], acc);
            acc = fmaf(xv.w, enc_w3[(k+3)*3+c], acc);
        }
        pool[t] = acc;
        out[OUT4 + (size_t)b*(N*3) + t] = acc;
    }
    __syncthreads();

    // ---- latent coords -> registers (const-indexed, stays in VGPRs) ----
    float kx[N], ky[N], kz[N];
    #pragma unroll
    for (int k=0;k<N;k++) { kx[k]=pool[k*3]; ky[k]=pool[k*3+1]; kz[k]=pool[k*3+2]; }

    // ---- skip connection -> registers ----
    float skipv[N];
    {
        float w0 = skip_w[t], w1 = skip_w[HID+t], w2 = skip_w[2*HID+t];
        float bias = skip_b[t];
        #pragma unroll
        for (int i=0;i<N;i++)
            skipv[i] = fmaf(kx[i], w0, fmaf(ky[i], w1, fmaf(kz[i], w2, bias)));
    }

    // ---- Gabriel adjacency via ballots (endpoints divergent, k-loop from regs) ----
    auto gab = [&](int i, int j)->bool {
        if (i == j) return false;
        float pix = pool[i*3], piy = pool[i*3+1];     // 4 divergent b32
        float pjx = pool[j*3], pjy = pool[j*3+1];
        float mx = (pix + pjx) * 0.5f, my = (piy + pjy) * 0.5f;
        float dx = pix - pjx, dy = piy - pjy;
        float r2 = (dx*dx + dy*dy) * 0.25f;
        bool g = true;
        #pragma unroll
        for (int k=0;k<N;k++) {
            float ex = kx[k] - mx, ey = ky[k] - my;
            bool ok = (k == i) || (k == j) || (ex*ex + ey*ey > r2);
            g = g && ok;
        }
        return g;
    };
    unsigned long long gb0 = __ballot(gab(i0, j0));
    unsigned long long gb1 = __ballot(gab(i1, j1));
    unsigned long long gb2 = __ballot((t < 16) && gab(i2, j2));
    auto gbit = [&](int p)->int {
        unsigned long long m = (p < 64) ? gb0 : ((p < 128) ? gb1 : gb2);
        return (int)((m >> (p & 63)) & 1ull);
    };
    const int adjA = gbit(p0) | gbit(j0*N+i0) | (i0 == j0);
    const int adjB = gbit(p1) | gbit(j1*N+i1) | (i1 == j1);
    const int adjC = (t < 16) ? (gbit(p2) | gbit(j2*N+i2) | (i2 == j2)) : 0;

    // ---- compact valid pairs ----
    auto mbcnt64 = [&](unsigned long long m)->int {
        return __builtin_amdgcn_mbcnt_hi((unsigned)(m >> 32),
               __builtin_amdgcn_mbcnt_lo((unsigned)m, 0));
    };
    const unsigned long long am0 = __ballot(adjA != 0);
    const unsigned long long am1 = __ballot(adjB != 0);
    const unsigned long long am2 = __ballot(adjC != 0);
    const int c0  = __popcll(am0);
    const int c01 = c0 + __popcll(am1);
    const int nv  = c01 + __popcll(am2);
    const int idx0 = mbcnt64(am0);
    const int idx1 = c0  + mbcnt64(am1);
    const int idx2 = c01 + mbcnt64(am2);
    if (adjA)               pairs8[idx0] = (unsigned char)p0;
    if (adjB && idx1 < 64)  pairs8[idx1] = (unsigned char)p1;
    if (adjC && idx2 < 64)  pairs8[idx2] = (unsigned char)p2;
    const bool ovB = adjB && (idx1 >= 64);
    const bool ovC = adjC && (idx2 >= 64);
    const int nvc = nv < 64 ? nv : 64;

    // ---- score (bf16 xl/xr; 16 div b128 + 16 bc per call; ROLLED) ----
    auto scoreAt = [&](int i, int j)->float {
        const unsigned* Lj = (const unsigned*)&xl16[j*XST];
        const unsigned* Ri = (const unsigned*)&xr16[i*XST];
        v2f a2 = z2;
        for (int h=0; h<HID; h+=8) {
            i4 lw = *reinterpret_cast<const i4*>(Lj + (h>>1));
            i4 rw = *reinterpret_cast<const i4*>(Ri + (h>>1));
            v4f aa = *reinterpret_cast<const v4f*>(&att_s[h]);
            v4f ab = *reinterpret_cast<const v4f*>(&att_s[h+4]);
            #pragma unroll
            for (int q=0; q<4; q++) {
                unsigned lu = (unsigned)lw[q], ru = (unsigned)rw[q];
                v2f xl2 = { __uint_as_float(lu << 16), __uint_as_float(lu & 0xffff0000u) };
                v2f xr2 = { __uint_as_float(ru << 16), __uint_as_float(ru & 0xffff0000u) };
                v2f s = xl2 + xr2;
                v2f l = __builtin_elementwise_fma(sl2, __builtin_elementwise_min(s, z2),
                                                  __builtin_elementwise_max(s, z2));
                v2f av = (q==0) ? aa.xy : (q==1) ? aa.zw : (q==2) ? ab.xy : ab.zw;
                a2 = __builtin_elementwise_fma(av, l, a2);
            }
        }
        return a2.x + a2.y;
    };

    // ---- GATv2 core: sparse exp(score) -> sum-normalized aggregate -> bf16 out ----
    auto gat_core = [&](const float* __restrict__ att, const float* __restrict__ gb,
                        unsigned short* __restrict__ out16, int useSkip) {
        att_s[t] = att[t];
        pool[t] = 0.f; pool[t+64] = 0.f;
        if (t < 16) pool[t+128] = 0.f;
        __syncthreads();
        if (t < nvc) {
            int p = pairs8[t];
            int i = (p * 171) >> 11;       // p/12 for p<144
            int j = p - i*N;
            pool[p] = __expf(scoreAt(i, j));
        }
        if (nv > 64) {
            if (ovB) pool[p1] = __expf(scoreAt(i1, j1));
            if (ovC) pool[p2] = __expf(scoreAt(i2, j2));
        }
        __syncthreads();
        {
            float xj[N];
            #pragma unroll
            for (int j=0;j<N;j++) xj[j] = bf2f(xl16[j*XST + t]);
            v4f X0 = {xj[0], xj[1], xj[2],  xj[3]};
            v4f X1 = {xj[4], xj[5], xj[6],  xj[7]};
            v4f X2 = {xj[8], xj[9], xj[10], xj[11]};
            float bias = gb[t];
            #pragma unroll
            for (int i=0;i<N;i++) {
                const v4f* ep = reinterpret_cast<const v4f*>(&pool[i*N]);
                v4f e0 = ep[0], e1 = ep[1], e2 = ep[2];
                float sum = ((e0.x+e0.y)+(e0.z+e0.w))
                          + ((e1.x+e1.y)+(e1.z+e1.w))
                          + ((e2.x+e2.y)+(e2.z+e2.w));
                v4f acc = __builtin_elementwise_fma(e0, X0,
                          __builtin_elementwise_fma(e1, X1, e2*X2));
                float r = bias + ((acc.x + acc.y) + (acc.z + acc.w)) / sum;
                if (useSkip) r = fmaf(ALPHA, skipv[i], r);
                out16[i*XST + t] = f2bf(fmaxf(r, 0.f));
            }
        }
        __syncthreads();
    };

    // ---- MFMA stage: xl16/xr16 <- xB16 @ {wl, wr}; A-frag = one 16B ds_read ----
    auto stage_mfma = [&](int matL) {
        const int m = t & 15, quad = t >> 4;
        const int mc = (m < N) ? m : 0;
        i4 aF0 = *reinterpret_cast<const i4*>(&xB16[mc*XST + quad*8]);
        i4 aF1 = *reinterpret_cast<const i4*>(&xB16[mc*XST + 32 + quad*8]);
        const i4* bbase = reinterpret_cast<const i4*>(wsT + 4096);
        #pragma unroll
        for (int mm=0; mm<2; mm++) {
            const i4* bp = bbase + (matL + mm)*512;
            v4f acc[4] = {z4, z4, z4, z4};
            #pragma unroll
            for (int nt=0; nt<4; nt++) {
                i4 b0 = bp[(0*4+nt)*64 + t];
                i4 b1 = bp[(1*4+nt)*64 + t];
                acc[nt] = __builtin_amdgcn_mfma_f32_16x16x32_bf16(as_v8s(aF0), as_v8s(b0), acc[nt], 0, 0, 0);
                acc[nt] = __builtin_amdgcn_mfma_f32_16x16x32_bf16(as_v8s(aF1), as_v8s(b1), acc[nt], 0, 0, 0);
            }
            unsigned short* dst = (mm == 0) ? xl16 : xr16;
            if (quad < 3) {
                #pragma unroll
                for (int nt=0; nt<4; nt++) {
                    #pragma unroll
                    for (int r=0; r<4; r++)
                        dst[(quad*4+r)*XST + nt*16 + m] = f2bf(acc[nt][r]);
                }
            }
        }
    };

    // ---- fallback stage (TW=false): VALU, global fp32 weights, bf16 x ----
    auto stage = [&](const float* __restrict__ wl, const float* __restrict__ wr) {
        v2f al[N], ar[N];
        #pragma unroll
        for (int i=0;i<N;i++) { al[i] = z2; ar[i] = z2; }
        for (int c=0;c<HID;c+=2) {
            v2f wlv = (v2f){wl[(c+0)*HID+t], wl[(c+1)*HID+t]};
            v2f wrv = (v2f){wr[(c+0)*HID+t], wr[(c+1)*HID+t]};
            #pragma unroll
            for (int i=0;i<N;i++) {
                unsigned xu = *(const unsigned*)&xB16[i*XST + c];
                v2f xv = { __uint_as_float(xu << 16), __uint_as_float(xu & 0xffff0000u) };
                al[i] = __builtin_elementwise_fma(xv, wlv, al[i]);
                ar[i] = __builtin_elementwise_fma(xv, wrv, ar[i]);
            }
        }
        #pragma unroll
        for (int i=0;i<N;i++) {
            xl16[i*XST + t] = f2bf(al[i].x + al[i].y);
            xr16[i*XST + t] = f2bf(ar[i].x + ar[i].y);
        }
    };

    // ---- GAT layer 1 (cin = 1; x0 = lat[:,2] in registers) ----
    {
        float wlv = g1_wl[t], wrv = g1_wr[t];
        #pragma unroll
        for (int i=0;i<N;i++) {
            xl16[i*XST + t] = f2bf(kz[i] * wlv);
            xr16[i*XST + t] = f2bf(kz[i] * wrv);
        }
    }
    gat_core(g1_att, g1_b, xB16, 0);        // x1 -> xB16

    // ---- GAT layer 2 ----
    if (TW) stage_mfma(0); else stage(g2_wl, g2_wr);
    gat_core(g2_att, g2_b, xB16, 0);        // x2 -> xB16 (persists for g3,g4)

    // ---- GAT layer 3 ----
    if (TW) stage_mfma(2); else stage(g3_wl, g3_wr);
    gat_core(g3_att, g3_b, xr16, 1);        // x3 -> xr16

    // ---- logits head: x3 @ lab_w + lab_b (reads xr16 before g4 stage overwrites;
    //      single-wave block -> DS in-order guarantees the ordering) ----
    if (t < N*4) {
        int i = t >> 2, c = t & 3;
        float acc = lab_b[c];
        const unsigned* xp = (const unsigned*)&xr16[i*XST];
        if (TW) {
            const float* lwT = wsT + 16384 + c*HID;
            for (int h=0;h<HID;h+=2) {
                unsigned xu = xp[h>>1];
                acc = fmaf(__uint_as_float(xu << 16), lwT[h], acc);
                acc = fmaf(__uint_as_float(xu & 0xffff0000u), lwT[h+1], acc);
            }
        } else {
            for (int h=0;h<HID;h+=2) {
                unsigned xu = xp[h>>1];
                acc = fmaf(__uint_as_float(xu << 16), lab_w[(h+0)*4+c], acc);
                acc = fmaf(__uint_as_float(xu & 0xffff0000u), lab_w[(h+1)*4+c], acc);
            }
        }
        out[OUT2 + (size_t)b*(N*4) + t] = acc;
    }

    // ---- GAT layer 4 (reads x2 from xB16) ----
    if (TW) stage_mfma(4); else stage(g4_wl, g4_wr);
    gat_core(g4_att, g4_b, xr16, 1);        // x4 -> xr16

    // ---- values head ----
    if (t < N) {
        float acc = val_b[0];
        const unsigned* xp = (const unsigned*)&xr16[t*XST];
        for (int h=0;h<HID;h+=2) {
            unsigned xu = xp[h>>1];
            acc = fmaf(__uint_as_float(xu << 16), val_w[h], acc);
            acc = fmaf(__uint_as_float(xu & 0xffff0000u), val_w[h+1], acc);
        }
        out[OUT3 + (size_t)b*N + t] = acc;
    }
}

extern "C" void kernel_launch(void* const* d_in, const int* in_sizes, int n_in,
                              void* d_out, int out_size, void* d_ws, size_t ws_size,
                              hipStream_t stream) {
    (void)in_sizes; (void)n_in; (void)out_size;
    const bool useT = (ws_size >= (16384 + 256)*sizeof(float));
    if (useT) {
        prep_kernel<<<dim3(113), dim3(64), 0, stream>>>(
            (const float*)d_in[3],
            (const float*)d_in[11], (const float*)d_in[12],
            (const float*)d_in[15], (const float*)d_in[16],
            (const float*)d_in[19], (const float*)d_in[20],
            (const float*)d_in[23],
            (float*)d_ws);
        gae_kernel<true><<<dim3(4096), dim3(64), 0, stream>>>(
            (const float*)d_in[0],
            (const float*)d_in[1],  (const float*)d_in[2],
            (const float*)d_in[3],  (const float*)d_in[4],
            (const float*)d_in[5],  (const float*)d_in[6],
            (const float*)d_in[7],  (const float*)d_in[8],  (const float*)d_in[9],  (const float*)d_in[10],
            (const float*)d_in[11], (const float*)d_in[12], (const float*)d_in[13], (const float*)d_in[14],
            (const float*)d_in[15], (const float*)d_in[16], (const float*)d_in[17], (const float*)d_in[18],
            (const float*)d_in[19], (const float*)d_in[20], (const float*)d_in[21], (const float*)d_in[22],
            (const float*)d_in[23], (const float*)d_in[24],
            (const float*)d_in[25], (const float*)d_in[26],
            (const float*)d_in[27], (const float*)d_in[28],
            (const float*)d_ws,
            (float*)d_out);
    } else {
        gae_kernel<false><<<dim3(4096), dim3(64), 0, stream>>>(
            (const float*)d_in[0],
            (const float*)d_in[1],  (const float*)d_in[2],
            (const float*)d_in[3],  (const float*)d_in[4],
            (const float*)d_in[5],  (const float*)d_in[6],
            (const float*)d_in[7],  (const float*)d_in[8],  (const float*)d_in[9],  (const float*)d_in[10],
            (const float*)d_in[11], (const float*)d_in[12], (const float*)d_in[13], (const float*)d_in[14],
            (const float*)d_in[15], (const float*)d_in[16], (const float*)d_in[17], (const float*)d_in[18],
            (const float*)d_in[19], (const float*)d_in[20], (const float*)d_in[21], (const float*)d_in[22],
            (const float*)d_in[23], (const float*)d_in[24],
            (const float*)d_in[25], (const float*)d_in[26],
            (const float*)d_in[27], (const float*)d_in[28],
            nullptr,
            (float*)d_out);
    }
}